// Round 7
// baseline (2119.073 us; speedup 1.0000x reference)
//
#include <hip/hip_runtime.h>

typedef __attribute__((ext_vector_type(8))) short short8;
typedef __attribute__((ext_vector_type(4))) float f32x4;

#define BATCH   131072
#define IND     300
#define MIDD    450
#define XS      328   // X LDS row stride (elems); 656B: bank step 4 -> 2-way alias (free)
#define HS      488   // H LDS row stride (elems); 976B: bank step 20 -> 2-way alias (free)
#define WXS     320   // W global row stride, K300-class: 640B = 64B-aligned rows
#define WHS     480   // W global row stride, K450-class: 960B = 64B-aligned rows
#define BM      48    // 48 rows/block -> LDS 78336B -> 2 blocks/CU
#define NTHR    512
#define NBLK    ((BATCH + BM - 1) / BM)   // 2731 (last block: 32 valid rows)

constexpr int SZ1 = 464 * WXS;    // [464][320] padded N450,K320 weights (row-major, bf16)
constexpr int SZ2 = 304 * WHS;    // [304][480] padded N300,K480 weights
constexpr int O_NOT1 = 0;
constexpr int O_NOT2 = SZ1;
constexpr int O_AND1 = SZ1 + SZ2;
constexpr int O_AND2 = 2 * SZ1 + SZ2;
constexpr int O_OR1  = 2 * SZ1 + 2 * SZ2;
constexpr int O_OR2  = 3 * SZ1 + 2 * SZ2;
constexpr int WS_ELEMS = 3 * SZ1 + 3 * SZ2;

constexpr int XBYTES = BM * XS * 2;           // 31488
constexpr int HBYTES = BM * HS * 2;           // 46848
constexpr int LDS_BYTES = XBYTES + HBYTES;    // 78336 -> 2 blocks/CU

__device__ __forceinline__ unsigned short f2b(float f) {
  unsigned u = __builtin_bit_cast(unsigned, f);
  u = (u + 0x7FFFu + ((u >> 16) & 1u)) >> 16;   // RNE
  return (unsigned short)u;
}
__device__ __forceinline__ float b2f(unsigned short h) {
  unsigned u = ((unsigned)h) << 16;
  return __builtin_bit_cast(float, u);
}
__device__ __forceinline__ f32x4 mfma16(short8 a, short8 b, f32x4 c) {
  asm("v_mfma_f32_16x16x32_bf16 %0, %1, %2, %0" : "+v"(c) : "v"(a), "v"(b));
  return c;
}

// ---- weight prep: f32 -> bf16, zero-padded, 64B-aligned rows; AND/OR W1 folded ----
__global__ void prep_weights(const float* __restrict__ nw1, const float* __restrict__ nw2,
                             const float* __restrict__ aw1, const float* __restrict__ aw2,
                             const float* __restrict__ ow1, const float* __restrict__ ow2,
                             unsigned short* __restrict__ ws)
{
  int idx = blockIdx.x * 256 + threadIdx.x;
  if (idx < 3 * SZ1) {
    int r = idx / SZ1, off = idx % SZ1;
    int n = off / WXS, k = off % WXS;
    float v = 0.f;
    if (n < MIDD && k < IND) {
      if (r == 0) v = nw1[n * IND + k];
      else {
        const float* s = (r == 1) ? aw1 : ow1;
        v = s[n * 2 * IND + k] + s[n * 2 * IND + IND + k];   // fold concat([x,x])
      }
    }
    int base = (r == 0) ? O_NOT1 : (r == 1) ? O_AND1 : O_OR1;
    ws[base + off] = f2b(v);
  } else if (idx < WS_ELEMS) {
    int i2 = idx - 3 * SZ1;
    int r = i2 / SZ2, off = i2 % SZ2;
    int n = off / WHS, k = off % WHS;
    float v = 0.f;
    if (n < IND && k < MIDD) {
      const float* s = (r == 0) ? nw2 : (r == 1) ? aw2 : ow2;
      v = s[n * MIDD + k];
    }
    int base = (r == 0) ? O_NOT2 : (r == 1) ? O_AND2 : O_OR2;
    ws[base + off] = f2b(v);
  }
}

// ---- one GEMM stage, split into 2 N-passes (NJ=2 per pass, acc 24 regs) ----
// A from LDS (ds_read_b128), B from L2 via depth-2 register pipeline. No per-K barriers.
// INPLACE (Hout==IN): hold pass outputs in regs, one internal sync, then write.
// Frags (16x16x32 bf16): A lane m=l&15,k=8*(l>>4)+i ; B lane n=l&15,k same
// D lane: n=l&15, m=(l>>4)*4+r  (validated rounds 1-3,5,6)
template <int KB, int NT, int N, bool MSE, bool INPLACE>
__device__ __forceinline__ void stage(const unsigned short* __restrict__ IN, int in_stride,
                                      const unsigned short* __restrict__ Wg, int wg_stride,
                                      const float* __restrict__ bias,
                                      unsigned short* __restrict__ Hout,
                                      const unsigned short* __restrict__ XT,
                                      float& sq, int rows, int tid, int wn, int l16, int lhi)
{
  const unsigned short* ap[3];
#pragma unroll
  for (int m = 0; m < 3; m++) ap[m] = IN + (m * 16 + l16) * in_stride + lhi * 8;

  unsigned hold[24];    // INPLACE only: [p][jj][m][r-pair] bf16-packed (DCE'd otherwise)

#pragma unroll
  for (int p = 0; p < 2; p++) {
    const bool v0 = (wn + 16 * p) < NT;
    const bool v1 = (wn + 8 + 16 * p) < NT;
    if (!v0) continue;                               // wave-uniform skip
    const unsigned short* bp[2];
    bp[0] = Wg + (wn + 16 * p) * 16 * wg_stride + l16 * wg_stride + lhi * 8;
    bp[1] = Wg + (wn + 8 + 16 * p) * 16 * wg_stride + l16 * wg_stride + lhi * 8;

    f32x4 acc[3][2];
#pragma unroll
    for (int m = 0; m < 3; m++)
#pragma unroll
      for (int j = 0; j < 2; j++) acc[m][j] = f32x4{0.f, 0.f, 0.f, 0.f};

    short8 a0[3], a1[3], b0[2], b1[2], b2[2];

#define LA_(buf, kk)                                                     \
    { _Pragma("unroll") for (int m = 0; m < 3; m++)                      \
        buf[m] = *(const short8*)(ap[m] + (kk) * 32); }
#define LB_(buf, kk)                                                     \
    { buf[0] = *(const short8*)(bp[0] + (kk) * 32);                      \
      if (v1) buf[1] = *(const short8*)(bp[1] + (kk) * 32); }

    LB_(b0, 0);
    LB_(b1, 1);
    LA_(a0, 0);

#pragma unroll
    for (int kb = 0; kb < KB; kb++) {
      short8* ac = (kb & 1) ? a1 : a0;
      short8* an = (kb & 1) ? a0 : a1;
      short8* bc = (kb % 3 == 0) ? b0 : (kb % 3 == 1) ? b1 : b2;
      short8* bn = ((kb + 2) % 3 == 0) ? b0 : ((kb + 2) % 3 == 1) ? b1 : b2;
      if (kb + 2 < KB) LB_(bn, kb + 2);     // depth-2 global prefetch (counted vmcnt)
      if (kb + 1 < KB) LA_(an, kb + 1);     // depth-1 LDS prefetch
#pragma unroll
      for (int m = 0; m < 3; m++) acc[m][0] = mfma16(ac[m], bc[0], acc[m][0]);
      if (v1) {
#pragma unroll
        for (int m = 0; m < 3; m++) acc[m][1] = mfma16(ac[m], bc[1], acc[m][1]);
      }
    }
#undef LA_
#undef LB_

    // per-pass epilogue
#pragma unroll
    for (int jj = 0; jj < 2; jj++) {
      const bool vj = jj ? v1 : v0;
      if (!vj) continue;
      int nt = wn + 8 * jj + 16 * p;
      int col = nt * 16 + l16;
      bool cval = col < N;
      float bv = cval ? bias[col] : 0.f;
#pragma unroll
      for (int m = 0; m < 3; m++) {
#pragma unroll
        for (int r2 = 0; r2 < 2; r2++) {
          float vlo = acc[m][jj][2 * r2] + bv;
          float vhi = acc[m][jj][2 * r2 + 1] + bv;
          vlo = vlo > 0.f ? vlo : 0.1f * vlo;
          vhi = vhi > 0.f ? vhi : 0.1f * vhi;
          int row = m * 16 + lhi * 4 + 2 * r2;
          if (MSE) {
            if (cval) {
              if (row < rows)     { float d = b2f(XT[row * XS + col]) - vlo; sq += d * d; }
              if (row + 1 < rows) { float d = b2f(XT[(row + 1) * XS + col]) - vhi; sq += d * d; }
            }
          } else if (!INPLACE) {
            if (cval) {
              Hout[row * HS + col] = f2b(vlo);
              Hout[(row + 1) * HS + col] = f2b(vhi);
            }
          } else {
            hold[((p * 2 + jj) * 3 + m) * 2 + r2] =
                (unsigned)f2b(vlo) | ((unsigned)f2b(vhi) << 16);
          }
        }
      }
    }
  }

  if (INPLACE) {
    __syncthreads();   // all waves done READING IN (==Hout) before any write
#pragma unroll
    for (int p = 0; p < 2; p++) {
#pragma unroll
      for (int jj = 0; jj < 2; jj++) {
        int nt = wn + 8 * jj + 16 * p;
        if (nt >= NT) continue;
        int col = nt * 16 + l16;
        if (col >= N) continue;
#pragma unroll
        for (int m = 0; m < 3; m++) {
#pragma unroll
          for (int r2 = 0; r2 < 2; r2++) {
            unsigned hv = hold[((p * 2 + jj) * 3 + m) * 2 + r2];
            int row = m * 16 + lhi * 4 + 2 * r2;
            Hout[row * HS + col] = (unsigned short)(hv & 0xFFFFu);
            Hout[(row + 1) * HS + col] = (unsigned short)(hv >> 16);
          }
        }
      }
    }
    if (N == IND) {
      // zero pad cols [300,320) so the next K=320 read sees zeros
      for (int i = tid; i < BM * 20; i += NTHR) {
        int r = i / 20, c = i - r * 20;
        Hout[r * HS + IND + c] = 0;
      }
    }
  }
}

__global__ __launch_bounds__(NTHR, 4)
void fused(const float* __restrict__ x, const unsigned short* __restrict__ ws,
           const float* __restrict__ nb1, const float* __restrict__ nb2,
           const float* __restrict__ ab1, const float* __restrict__ ab2,
           const float* __restrict__ ob1, const float* __restrict__ ob2,
           float* __restrict__ out)
{
  extern __shared__ __align__(16) char smem[];
  unsigned short* X = (unsigned short*)smem;                 // [48][XS]
  unsigned short* H = (unsigned short*)(smem + XBYTES);      // [48][HS]
  __shared__ float wsum[8];
  int tid = threadIdx.x, wid = tid >> 6, lane = tid & 63;
  int l16 = lane & 15, lhi = lane >> 4;

  // zero X+H (K-pad columns and tail rows must be 0)
  for (int i = tid; i < LDS_BYTES / 4; i += NTHR) ((unsigned*)smem)[i] = 0u;
  __syncthreads();

  int row0 = blockIdx.x * BM;
  int rows = (row0 + BM <= BATCH) ? BM : (BATCH - row0);
  for (int i = tid; i < rows * IND; i += NTHR) {
    int r = i / IND, c = i - r * IND;
    X[r * XS + c] = f2b(x[(size_t)(row0 + r) * IND + c]);
  }
  __syncthreads();

  float sq = 0.f;
  // NOT(NOT(x))
  stage<10, 29, MIDD, false, false>(X, XS, ws + O_NOT1, WXS, nb1, H, X, sq, rows, tid, wid, l16, lhi);
  __syncthreads();
  stage<15, 19, IND,  false, true >(H, HS, ws + O_NOT2, WHS, nb2, H, X, sq, rows, tid, wid, l16, lhi);
  __syncthreads();
  stage<10, 29, MIDD, false, true >(H, HS, ws + O_NOT1, WXS, nb1, H, X, sq, rows, tid, wid, l16, lhi);
  __syncthreads();
  stage<15, 19, IND,  true,  false>(H, HS, ws + O_NOT2, WHS, nb2, H, X, sq, rows, tid, wid, l16, lhi);
  __syncthreads();
  // AND (folded W1)
  stage<10, 29, MIDD, false, false>(X, XS, ws + O_AND1, WXS, ab1, H, X, sq, rows, tid, wid, l16, lhi);
  __syncthreads();
  stage<15, 19, IND,  true,  false>(H, HS, ws + O_AND2, WHS, ab2, H, X, sq, rows, tid, wid, l16, lhi);
  __syncthreads();
  // OR (folded W1)
  stage<10, 29, MIDD, false, false>(X, XS, ws + O_OR1,  WXS, ob1, H, X, sq, rows, tid, wid, l16, lhi);
  __syncthreads();
  stage<15, 19, IND,  true,  false>(H, HS, ws + O_OR2,  WHS, ob2, H, X, sq, rows, tid, wid, l16, lhi);

#pragma unroll
  for (int off = 32; off > 0; off >>= 1) sq += __shfl_down(sq, off);
  if (lane == 0) wsum[wid] = sq;
  __syncthreads();
  if (tid == 0) {
    float s = 0.f;
#pragma unroll
    for (int w = 0; w < 8; w++) s += wsum[w];
    atomicAdd(out, s);
  }
}

__global__ void finalize(float* out) {
  out[0] *= (1.0f / (3.0f * (float)BATCH * (float)IND));
}

extern "C" void kernel_launch(void* const* d_in, const int* in_sizes, int n_in,
                              void* d_out, int out_size, void* d_ws, size_t ws_size,
                              hipStream_t stream) {
  const float* x   = (const float*)d_in[0];
  const float* nw1 = (const float*)d_in[1];
  const float* nb1 = (const float*)d_in[2];
  const float* nw2 = (const float*)d_in[3];
  const float* nb2 = (const float*)d_in[4];
  const float* aw1 = (const float*)d_in[5];
  const float* ab1 = (const float*)d_in[6];
  const float* aw2 = (const float*)d_in[7];
  const float* ab2 = (const float*)d_in[8];
  const float* ow1 = (const float*)d_in[9];
  const float* ob1 = (const float*)d_in[10];
  const float* ow2 = (const float*)d_in[11];
  const float* ob2 = (const float*)d_in[12];
  unsigned short* ws = (unsigned short*)d_ws;
  float* out = (float*)d_out;

  hipMemsetAsync(d_out, 0, sizeof(float), stream);

  int prep_blocks = (WS_ELEMS + 255) / 256;
  prep_weights<<<prep_blocks, 256, 0, stream>>>(nw1, nw2, aw1, aw2, ow1, ow2, ws);

  hipFuncSetAttribute((const void*)fused,
                      hipFuncAttributeMaxDynamicSharedMemorySize, LDS_BYTES);
  fused<<<NBLK, NTHR, LDS_BYTES, stream>>>(x, ws, nb1, nb2, ab1, ab2, ob1, ob2, out);

  finalize<<<1, 1, 0, stream>>>(out);
}

// Round 8
// 610.290 us; speedup vs baseline: 3.4722x; 3.4722x over previous
//
#include <hip/hip_runtime.h>

typedef __attribute__((ext_vector_type(8))) short short8;
typedef __attribute__((ext_vector_type(4))) float f32x4;

#define BATCH   131072
#define IND     300
#define MIDD    450
#define XS      328   // X LDS row stride (elems); 656B: bank step 4 -> 2-way alias (free)
#define HS      488   // H LDS row stride (elems); 976B: bank step 20 -> 2-way alias (free)
#define WXS     320   // W global row stride, K300-class: 640B = 64B-aligned rows
#define WHS     480   // W global row stride, K450-class: 960B = 64B-aligned rows
#define BM      64
#define NTHR    512

constexpr int SZ1 = 464 * WXS;    // [464][320] padded N450,K320 weights (row-major, bf16)
constexpr int SZ2 = 304 * WHS;    // [304][480] padded N300,K480 weights
constexpr int O_NOT1 = 0;
constexpr int O_NOT2 = SZ1;
constexpr int O_AND1 = SZ1 + SZ2;
constexpr int O_AND2 = 2 * SZ1 + SZ2;
constexpr int O_OR1  = 2 * SZ1 + 2 * SZ2;
constexpr int O_OR2  = 3 * SZ1 + 2 * SZ2;
constexpr int WS_ELEMS = 3 * SZ1 + 3 * SZ2;

constexpr int XBYTES = BM * XS * 2;           // 41984
constexpr int HBYTES = BM * HS * 2;           // 62464
constexpr int LDS_BYTES = XBYTES + HBYTES;    // 104448

__device__ __forceinline__ unsigned short f2b(float f) {
  unsigned u = __builtin_bit_cast(unsigned, f);
  u = (u + 0x7FFFu + ((u >> 16) & 1u)) >> 16;   // RNE
  return (unsigned short)u;
}
__device__ __forceinline__ float b2f(unsigned short h) {
  unsigned u = ((unsigned)h) << 16;
  return __builtin_bit_cast(float, u);
}
__device__ __forceinline__ f32x4 mfma16(short8 a, short8 b, f32x4 c) {
  asm("v_mfma_f32_16x16x32_bf16 %0, %1, %2, %0" : "+v"(c) : "v"(a), "v"(b));
  return c;
}

// ---- weight prep: f32 -> bf16, zero-padded, 64B-aligned rows; AND/OR W1 folded ----
__global__ void prep_weights(const float* __restrict__ nw1, const float* __restrict__ nw2,
                             const float* __restrict__ aw1, const float* __restrict__ aw2,
                             const float* __restrict__ ow1, const float* __restrict__ ow2,
                             unsigned short* __restrict__ ws)
{
  int idx = blockIdx.x * 256 + threadIdx.x;
  if (idx < 3 * SZ1) {
    int r = idx / SZ1, off = idx % SZ1;
    int n = off / WXS, k = off % WXS;
    float v = 0.f;
    if (n < MIDD && k < IND) {
      if (r == 0) v = nw1[n * IND + k];
      else {
        const float* s = (r == 1) ? aw1 : ow1;
        v = s[n * 2 * IND + k] + s[n * 2 * IND + IND + k];   // fold concat([x,x])
      }
    }
    int base = (r == 0) ? O_NOT1 : (r == 1) ? O_AND1 : O_OR1;
    ws[base + off] = f2b(v);
  } else if (idx < WS_ELEMS) {
    int i2 = idx - 3 * SZ1;
    int r = i2 / SZ2, off = i2 % SZ2;
    int n = off / WHS, k = off % WHS;
    float v = 0.f;
    if (n < IND && k < MIDD) {
      const float* s = (r == 0) ? nw2 : (r == 1) ? aw2 : ow2;
      v = s[n * MIDD + k];
    }
    int base = (r == 0) ? O_NOT2 : (r == 1) ? O_AND2 : O_OR2;
    ws[base + off] = f2b(v);
  }
}

// ---- one GEMM stage: OUT[64][N] = leaky(IN[64][K] @ W^T + b); MSE variant fuses vs X ----
// A from LDS via 3-buffer (depth-2) pipeline; B from L2 via 5-buffer (depth-4) register
// pipeline (counted vmcnt). No per-K-step barriers.
// 16x16x32 bf16 frags: A lane: m=l&15,k=8*(l>>4)+i ; B lane: n=l&15,k=8*(l>>4)+i
// D lane: n=l&15, m=(l>>4)*4+r  (validated rounds 1-3,5,6)
template <int KB, int NT, int N, bool MSE>
__device__ __forceinline__ void stage(const unsigned short* __restrict__ IN, int in_stride,
                                      const unsigned short* __restrict__ Wg, int wg_stride,
                                      const float* __restrict__ bias,
                                      unsigned short* __restrict__ Hout,
                                      const unsigned short* __restrict__ XT,
                                      float& sq, int tid, int wn, int l16, int lhi)
{
  constexpr int NJ = (NT + 7) / 8;
  f32x4 acc[4][NJ];
#pragma unroll
  for (int m = 0; m < 4; m++)
#pragma unroll
    for (int j = 0; j < NJ; j++) acc[m][j] = f32x4{0.f, 0.f, 0.f, 0.f};

  const unsigned short* ap[4];
#pragma unroll
  for (int m = 0; m < 4; m++) ap[m] = IN + (m * 16 + l16) * in_stride + lhi * 8;
  const unsigned short* bp[NJ];
#pragma unroll
  for (int j = 0; j < NJ; j++) {
    int nt = wn + 8 * j;
    int row = (nt < NT ? nt : 0) * 16 + l16;      // clamp invalid tiles to row 0
    bp[j] = Wg + row * wg_stride + lhi * 8;
  }

  short8 a0[4], a1[4], a2[4];
  short8 b0[NJ], b1[NJ], b2[NJ], b3[NJ], b4[NJ];

#define LA_(buf, kk)                                                     \
  { _Pragma("unroll") for (int m = 0; m < 4; m++)                        \
      buf[m] = *(const short8*)(ap[m] + (kk) * 32); }
#define LB_(buf, kk)                                                     \
  { _Pragma("unroll") for (int j = 0; j < NJ; j++)                       \
      if (wn + 8 * j < NT) buf[j] = *(const short8*)(bp[j] + (kk) * 32); }

  // prologue: 4 B-slices and 2 A-slices in flight (KB >= 10 always)
  LB_(b0, 0); LB_(b1, 1); LB_(b2, 2); LB_(b3, 3);
  LA_(a0, 0); LA_(a1, 1);

#pragma unroll
  for (int kb = 0; kb < KB; kb++) {
    short8* ac = (kb % 3 == 0) ? a0 : (kb % 3 == 1) ? a1 : a2;
    short8* an = ((kb + 2) % 3 == 0) ? a0 : ((kb + 2) % 3 == 1) ? a1 : a2;
    short8* bc = (kb % 5 == 0) ? b0 : (kb % 5 == 1) ? b1 : (kb % 5 == 2) ? b2
               : (kb % 5 == 3) ? b3 : b4;
    short8* bn = ((kb + 4) % 5 == 0) ? b0 : ((kb + 4) % 5 == 1) ? b1
               : ((kb + 4) % 5 == 2) ? b2 : ((kb + 4) % 5 == 3) ? b3 : b4;
    if (kb + 4 < KB) LB_(bn, kb + 4);     // depth-4 global prefetch (counted vmcnt)
    if (kb + 2 < KB) LA_(an, kb + 2);     // depth-2 LDS prefetch
#pragma unroll
    for (int j = 0; j < NJ; j++) {
      if (wn + 8 * j < NT) {
#pragma unroll
        for (int m = 0; m < 4; m++) acc[m][j] = mfma16(ac[m], bc[j], acc[m][j]);
      }
    }
  }
#undef LA_
#undef LB_

  if (!MSE) __syncthreads();   // in-place H overwrite: all waves done reading IN

#pragma unroll
  for (int j = 0; j < NJ; j++) {
    int nt = wn + 8 * j;
    if (nt >= NT) continue;
    int col = nt * 16 + l16;
    bool valid = col < N;
    float bv = valid ? bias[col] : 0.f;
#pragma unroll
    for (int m = 0; m < 4; m++) {
#pragma unroll
      for (int r = 0; r < 4; r++) {
        int row = m * 16 + lhi * 4 + r;
        float v = acc[m][j][r] + bv;
        v = v > 0.f ? v : 0.1f * v;
        if (MSE) {
          if (valid) { float d = b2f(XT[row * XS + col]) - v; sq += d * d; }
        } else {
          if (valid) Hout[row * HS + col] = f2b(v);
        }
      }
    }
  }
  if (!MSE && N == IND) {
    // zero pad cols [300,320) so the next K=320 read sees zeros
    for (int i = tid; i < BM * 20; i += NTHR) {
      int r = i / 20, c = i - r * 20;
      Hout[r * HS + IND + c] = 0;
    }
  }
}

__global__ __launch_bounds__(NTHR)
void fused(const float* __restrict__ x, const unsigned short* __restrict__ ws,
           const float* __restrict__ nb1, const float* __restrict__ nb2,
           const float* __restrict__ ab1, const float* __restrict__ ab2,
           const float* __restrict__ ob1, const float* __restrict__ ob2,
           float* __restrict__ out)
{
  extern __shared__ __align__(16) char smem[];
  unsigned short* X = (unsigned short*)smem;                 // [64][XS]
  unsigned short* H = (unsigned short*)(smem + XBYTES);      // [64][HS]
  __shared__ float wsum[8];
  int tid = threadIdx.x, wid = tid >> 6, lane = tid & 63;
  int l16 = lane & 15, lhi = lane >> 4;

  // zero X+H (K-pad columns must be 0)
  for (int i = tid; i < LDS_BYTES / 4; i += NTHR) ((unsigned*)smem)[i] = 0u;
  __syncthreads();

  int row0 = blockIdx.x * BM;
  for (int i = tid; i < BM * IND; i += NTHR) {
    int r = i / IND, c = i - r * IND;
    X[r * XS + c] = f2b(x[(size_t)(row0 + r) * IND + c]);
  }
  __syncthreads();

  float sq = 0.f;
  // NOT(NOT(x))
  stage<10, 29, MIDD, false>(X, XS, ws + O_NOT1, WXS, nb1, H, X, sq, tid, wid, l16, lhi);
  __syncthreads();
  stage<15, 19, IND,  false>(H, HS, ws + O_NOT2, WHS, nb2, H, X, sq, tid, wid, l16, lhi);
  __syncthreads();
  stage<10, 29, MIDD, false>(H, HS, ws + O_NOT1, WXS, nb1, H, X, sq, tid, wid, l16, lhi);
  __syncthreads();
  stage<15, 19, IND,  true >(H, HS, ws + O_NOT2, WHS, nb2, H, X, sq, tid, wid, l16, lhi);
  __syncthreads();
  // AND (folded W1)
  stage<10, 29, MIDD, false>(X, XS, ws + O_AND1, WXS, ab1, H, X, sq, tid, wid, l16, lhi);
  __syncthreads();
  stage<15, 19, IND,  true >(H, HS, ws + O_AND2, WHS, ab2, H, X, sq, tid, wid, l16, lhi);
  __syncthreads();
  // OR (folded W1)
  stage<10, 29, MIDD, false>(X, XS, ws + O_OR1,  WXS, ob1, H, X, sq, tid, wid, l16, lhi);
  __syncthreads();
  stage<15, 19, IND,  true >(H, HS, ws + O_OR2,  WHS, ob2, H, X, sq, tid, wid, l16, lhi);

#pragma unroll
  for (int off = 32; off > 0; off >>= 1) sq += __shfl_down(sq, off);
  if (lane == 0) wsum[wid] = sq;
  __syncthreads();
  if (tid == 0) {
    float s = 0.f;
#pragma unroll
    for (int w = 0; w < 8; w++) s += wsum[w];
    atomicAdd(out, s);
  }
}

__global__ void finalize(float* out) {
  out[0] *= (1.0f / (3.0f * (float)BATCH * (float)IND));
}

extern "C" void kernel_launch(void* const* d_in, const int* in_sizes, int n_in,
                              void* d_out, int out_size, void* d_ws, size_t ws_size,
                              hipStream_t stream) {
  const float* x   = (const float*)d_in[0];
  const float* nw1 = (const float*)d_in[1];
  const float* nb1 = (const float*)d_in[2];
  const float* nw2 = (const float*)d_in[3];
  const float* nb2 = (const float*)d_in[4];
  const float* aw1 = (const float*)d_in[5];
  const float* ab1 = (const float*)d_in[6];
  const float* aw2 = (const float*)d_in[7];
  const float* ab2 = (const float*)d_in[8];
  const float* ow1 = (const float*)d_in[9];
  const float* ob1 = (const float*)d_in[10];
  const float* ow2 = (const float*)d_in[11];
  const float* ob2 = (const float*)d_in[12];
  unsigned short* ws = (unsigned short*)d_ws;
  float* out = (float*)d_out;

  hipMemsetAsync(d_out, 0, sizeof(float), stream);

  int prep_blocks = (WS_ELEMS + 255) / 256;
  prep_weights<<<prep_blocks, 256, 0, stream>>>(nw1, nw2, aw1, aw2, ow1, ow2, ws);

  hipFuncSetAttribute((const void*)fused,
                      hipFuncAttributeMaxDynamicSharedMemorySize, LDS_BYTES);
  fused<<<BATCH / BM, NTHR, LDS_BYTES, stream>>>(x, ws, nb1, nb2, ab1, ab2, ob1, ob2, out);

  finalize<<<1, 1, 0, stream>>>(out);
}